// Round 2
// baseline (16704.582 us; speedup 1.0000x reference)
//
#include <hip/hip_runtime.h>
#include <hip/hip_fp16.h>

#define BB 32
#define LL 512
#define HH 1024
#define NL 4
#define RS 8   // h ring slots per layer

typedef _Float16 f16x8 __attribute__((ext_vector_type(8)));
typedef float    f32x4 __attribute__((ext_vector_type(4)));
typedef float    f32x2 __attribute__((ext_vector_type(2)));

__device__ __forceinline__ f16x8 cvt8(const float* __restrict__ p) {
  f32x4 lo = *reinterpret_cast<const f32x4*>(p);
  f32x4 hi = *reinterpret_cast<const f32x4*>(p + 4);
  f16x8 r;
#pragma unroll
  for (int e = 0; e < 4; ++e) { r[e] = (_Float16)lo[e]; r[e + 4] = (_Float16)hi[e]; }
  return r;
}

// Persistent pipeline: 256 blocks (= #CUs), block b: layer l = b>>6, cols [ (b&63)*16, +16 ).
// 4 waves split k (512 each of 2×1024). Weights in VGPRs. Flag dataflow sync.
__global__ __launch_bounds__(256, 1) void rnn_persist(
    const float* __restrict__ x,   // [B][L][H] f32
    const float* __restrict__ h0,  // [NL][B][H] f32
    const float* __restrict__ WI,  // [NL][H][H] f32
    const float* __restrict__ BI,  // [NL][H]
    const float* __restrict__ WH,  // [NL][H][H] f32
    const float* __restrict__ BH,  // [NL][H]
    float* __restrict__ out,       // [B][L][H] f32 ++ hfinal [NL][B][H]
    _Float16* __restrict__ hbuf,   // [NL][RS][B][H] f16 ring
    unsigned* __restrict__ prod,   // [NL][LL]
    unsigned* __restrict__ cons) { // [NL][LL]
  const int l    = blockIdx.x >> 6;
  const int c0   = (blockIdx.x & 63) * 16;
  const int tid  = threadIdx.x;
  const int w    = tid >> 6;       // wave 0..3 -> k chunk
  const int lane = tid & 63;
  const int crow = lane & 15;      // A row / B row(=out col) within tile
  const int kgrp = lane >> 4;      // k subgroup
  const int kb   = w * 256 + kgrp * 8;  // lane's base k within H

  // ---- weight fragments -> registers (once per call) ----
  f16x8 bi[8], bh[8];
  {
    const float* wi = WI + ((size_t)l * HH + c0 + crow) * HH + kb;
    const float* wh = WH + ((size_t)l * HH + c0 + crow) * HH + kb;
#pragma unroll
    for (int j = 0; j < 8; ++j) { bi[j] = cvt8(wi + j * 32); bh[j] = cvt8(wh + j * 32); }
  }

  // ---- reduce-phase assignment: thread -> (batch row rb, col pair cp) ----
  const int rb = tid >> 3;         // 0..31
  const int cp = (tid & 7) * 2;    // 0,2,...,14
  const float bias0 = BI[l * HH + c0 + cp]     + BH[l * HH + c0 + cp];
  const float bias1 = BI[l * HH + c0 + cp + 1] + BH[l * HH + c0 + cp + 1];

  __shared__ float red[4][2][16][17];

  for (int t = 0; t < LL; ++t) {
    // ---------- wait for dependencies ----------
    if (tid == 0) {
      if (t > 0)
        while (__hip_atomic_load(&prod[l * LL + t - 1], __ATOMIC_ACQUIRE,
                                 __HIP_MEMORY_SCOPE_AGENT) < 64u)
          __builtin_amdgcn_s_sleep(1);
      if (l > 0)
        while (__hip_atomic_load(&prod[(l - 1) * LL + t], __ATOMIC_ACQUIRE,
                                 __HIP_MEMORY_SCOPE_AGENT) < 64u)
          __builtin_amdgcn_s_sleep(1);
      if (t >= RS) {
        const unsigned cexp = (l < NL - 1) ? 128u : 64u;
        while (__hip_atomic_load(&cons[l * LL + t - RS], __ATOMIC_ACQUIRE,
                                 __HIP_MEMORY_SCOPE_AGENT) < cexp)
          __builtin_amdgcn_s_sleep(1);
      }
    }
    __syncthreads();

    // ---------- load A fragments (independent 16B loads) ----------
    f16x8 ai0[8], ai1[8], ah0[8], ah1[8];
    if (l == 0) {
      const float* r0 = x + ((size_t)crow * LL + t) * HH + kb;
      const float* r1 = x + ((size_t)(crow + 16) * LL + t) * HH + kb;
#pragma unroll
      for (int j = 0; j < 8; ++j) { ai0[j] = cvt8(r0 + j * 32); ai1[j] = cvt8(r1 + j * 32); }
    } else {
      const _Float16* base =
          hbuf + ((size_t)((l - 1) * RS + (t & (RS - 1))) * BB) * HH + kb;
#pragma unroll
      for (int j = 0; j < 8; ++j) {
        ai0[j] = *reinterpret_cast<const f16x8*>(base + (size_t)crow * HH + j * 32);
        ai1[j] = *reinterpret_cast<const f16x8*>(base + (size_t)(crow + 16) * HH + j * 32);
      }
    }
    if (t == 0) {
      const float* r0 = h0 + ((size_t)l * BB + crow) * HH + kb;
      const float* r1 = r0 + (size_t)16 * HH;
#pragma unroll
      for (int j = 0; j < 8; ++j) { ah0[j] = cvt8(r0 + j * 32); ah1[j] = cvt8(r1 + j * 32); }
    } else {
      const _Float16* base =
          hbuf + ((size_t)(l * RS + ((t - 1) & (RS - 1))) * BB) * HH + kb;
#pragma unroll
      for (int j = 0; j < 8; ++j) {
        ah0[j] = *reinterpret_cast<const f16x8*>(base + (size_t)crow * HH + j * 32);
        ah1[j] = *reinterpret_cast<const f16x8*>(base + (size_t)(crow + 16) * HH + j * 32);
      }
    }

    // ---------- MFMA: 4 independent acc chains ----------
    f32x4 c0i = {0.f, 0.f, 0.f, 0.f}, c1i = {0.f, 0.f, 0.f, 0.f};
    f32x4 c0h = {0.f, 0.f, 0.f, 0.f}, c1h = {0.f, 0.f, 0.f, 0.f};
#pragma unroll
    for (int j = 0; j < 8; ++j) {
      c0i = __builtin_amdgcn_mfma_f32_16x16x32_f16(ai0[j], bi[j], c0i, 0, 0, 0);
      c1i = __builtin_amdgcn_mfma_f32_16x16x32_f16(ai1[j], bi[j], c1i, 0, 0, 0);
      c0h = __builtin_amdgcn_mfma_f32_16x16x32_f16(ah0[j], bh[j], c0h, 0, 0, 0);
      c1h = __builtin_amdgcn_mfma_f32_16x16x32_f16(ah1[j], bh[j], c1h, 0, 0, 0);
    }
    const f32x4 s0 = c0i + c0h;
    const f32x4 s1 = c1i + c1h;

    // ---------- cross-wave reduce via LDS ----------
#pragma unroll
    for (int r = 0; r < 4; ++r) {
      red[w][0][kgrp * 4 + r][crow] = s0[r];
      red[w][1][kgrp * 4 + r][crow] = s1[r];
    }
    __syncthreads();

    float v0 = 0.f, v1 = 0.f;
#pragma unroll
    for (int w2 = 0; w2 < 4; ++w2) {
      v0 += red[w2][rb >> 4][rb & 15][cp];
      v1 += red[w2][rb >> 4][rb & 15][cp + 1];
    }
    v0 = tanhf(v0 + bias0);
    v1 = tanhf(v1 + bias1);

    {  // h ring store (2×f16 = 4B)
      _Float16 p2[2] = {(_Float16)v0, (_Float16)v1};
      unsigned u;
      __builtin_memcpy(&u, p2, 4);
      *reinterpret_cast<unsigned*>(
          hbuf + ((size_t)(l * RS + (t & (RS - 1))) * BB + rb) * HH + c0 + cp) = u;
    }
    if (l == NL - 1) {
      f32x2 v = {v0, v1};
      *reinterpret_cast<f32x2*>(out + ((size_t)rb * LL + t) * HH + c0 + cp) = v;
    }
    if (t == LL - 1) {
      f32x2 v = {v0, v1};
      *reinterpret_cast<f32x2*>(out + (size_t)BB * LL * HH +
                                ((size_t)l * BB + rb) * HH + c0 + cp) = v;
    }
    __syncthreads();   // drains all waves' stores to L2; also guards red[] reuse

    // ---------- signal ----------
    if (tid == 0) {
      // release => L2 writeback before the add becomes visible (cross-XCD safe)
      __hip_atomic_fetch_add(&prod[l * LL + t], 1u, __ATOMIC_RELEASE,
                             __HIP_MEMORY_SCOPE_AGENT);
      if (l > 0)
        __hip_atomic_fetch_add(&cons[(l - 1) * LL + t], 1u, __ATOMIC_RELAXED,
                               __HIP_MEMORY_SCOPE_AGENT);
      if (t > 0)
        __hip_atomic_fetch_add(&cons[l * LL + t - 1], 1u, __ATOMIC_RELAXED,
                               __HIP_MEMORY_SCOPE_AGENT);
    }
  }
}

extern "C" void kernel_launch(void* const* d_in, const int* in_sizes, int n_in,
                              void* d_out, int out_size, void* d_ws, size_t ws_size,
                              hipStream_t stream) {
  const float* x  = (const float*)d_in[0];
  const float* h0 = (const float*)d_in[1];
  const float* WI = (const float*)d_in[2];
  const float* BI = (const float*)d_in[3];
  const float* WH = (const float*)d_in[4];
  const float* BH = (const float*)d_in[5];
  float* out = (float*)d_out;

  const size_t hbytes = (size_t)NL * RS * BB * HH * sizeof(_Float16);  // 2 MB
  _Float16* hbuf = (_Float16*)d_ws;
  unsigned* prod = (unsigned*)((char*)d_ws + hbytes);
  unsigned* cons = prod + NL * LL;

  hipMemsetAsync(prod, 0, (size_t)2 * NL * LL * sizeof(unsigned), stream);
  rnn_persist<<<256, 256, 0, stream>>>(x, h0, WI, BI, WH, BH, out, hbuf, prod, cons);
}

// Round 3
// 7961.352 us; speedup vs baseline: 2.0982x; 2.0982x over previous
//
#include <hip/hip_runtime.h>
#include <hip/hip_fp16.h>

#define BB 32
#define LL 512
#define HH 1024
#define NL 4
#define RS 8     // h ring slots per layer
#define TPL 32   // blocks (tiles) per layer
#define CPB 32   // output cols per block

typedef _Float16 f16x8 __attribute__((ext_vector_type(8)));
typedef _Float16 f16x4 __attribute__((ext_vector_type(4)));
typedef float    f32x4 __attribute__((ext_vector_type(4)));

__device__ __forceinline__ f16x8 cvt8(const float* __restrict__ p) {
  f32x4 lo = *reinterpret_cast<const f32x4*>(p);
  f32x4 hi = *reinterpret_cast<const f32x4*>(p + 4);
  f16x8 r;
#pragma unroll
  for (int e = 0; e < 4; ++e) { r[e] = (_Float16)lo[e]; r[e + 4] = (_Float16)hi[e]; }
  return r;
}

// Persistent pipeline, 128 active blocks: layer = blockIdx&7 (XCD-pinning
// heuristic: all 32 blocks of a layer land on one XCD under round-robin
// mapping; correctness never depends on it). Each block: 32 cols, weights in
// VGPRs, 4 waves split k (2048 total: waves 0-1 = input GEMM, 2-3 = hidden).
// Sync: store-only monotonic flags (no RMW), agent scope.
__global__ __launch_bounds__(256, 1) void rnn_persist(
    const float* __restrict__ x,   // [B][L][H] f32
    const float* __restrict__ h0,  // [NL][B][H] f32
    const float* __restrict__ WI,  // [NL][H][H] f32
    const float* __restrict__ BI,  // [NL][H]
    const float* __restrict__ WH,  // [NL][H][H] f32
    const float* __restrict__ BH,  // [NL][H]
    float* __restrict__ out,       // [B][L][H] f32 ++ hfinal [NL][B][H]
    _Float16* __restrict__ hbuf,   // [NL][RS][B][H] f16 ring
    unsigned* __restrict__ pflag) {// [NL][TPL] progress: t+1 after step t
  const int l = blockIdx.x & 7;
  if (l >= NL) return;
  const int tile = blockIdx.x >> 3;   // 0..31
  const int c0   = tile * CPB;
  const int tid  = threadIdx.x;
  const int w    = tid >> 6;          // wave 0..3
  const int lane = tid & 63;
  const int crow = lane & 15;
  const int kgrp = lane >> 4;
  const int kofs = (w & 1) * 512;     // k offset within the 1024-wide matrix

  // ---- weight fragments -> registers (once) ----
  // wave 0,1: WI k[0,512)/[512,1024); wave 2,3: WH same. 2 col-subtiles x 16 k-iters.
  f16x8 wfrag[2][16];
  {
    const float* Wb = (w < 2 ? WI : WH) + (size_t)l * HH * HH;
#pragma unroll
    for (int ct = 0; ct < 2; ++ct) {
      const float* wr = Wb + (size_t)(c0 + ct * 16 + crow) * HH + kofs + kgrp * 8;
#pragma unroll
      for (int j = 0; j < 16; ++j) wfrag[ct][j] = cvt8(wr + j * 32);
    }
  }

  // ---- epilogue assignment: thread -> (batch row rb, 4 cols at c4) ----
  const int rb = tid >> 3;          // 0..31
  const int c4 = (tid & 7) * 4;     // 0,4,...,28
  float bias[4];
#pragma unroll
  for (int j = 0; j < 4; ++j)
    bias[j] = BI[l * HH + c0 + c4 + j] + BH[l * HH + c0 + c4 + j];

  __shared__ float red[4][2][16][34];   // [wave][rowtile][row][col+pad]

  for (int t = 0; t < LL; ++t) {
    // ---------- wait for dependencies (store-only flags, no RMW) ----------
    if (tid < 64) {
      const int L = tid & 31;
      if (t > 0)   // own layer finished t-1
        while (__hip_atomic_load(&pflag[l * TPL + L], __ATOMIC_RELAXED,
                                 __HIP_MEMORY_SCOPE_AGENT) < (unsigned)t)
          __builtin_amdgcn_s_sleep(2);
      if (l > 0)   // layer l-1 finished t
        while (__hip_atomic_load(&pflag[(l - 1) * TPL + L], __ATOMIC_RELAXED,
                                 __HIP_MEMORY_SCOPE_AGENT) < (unsigned)(t + 1))
          __builtin_amdgcn_s_sleep(2);
      if (l < NL - 1 && t >= RS)  // WAR: layer l+1 consumed ring slot t-RS
        while (__hip_atomic_load(&pflag[(l + 1) * TPL + L], __ATOMIC_RELAXED,
                                 __HIP_MEMORY_SCOPE_AGENT) < (unsigned)(t - (RS - 1)))
          __builtin_amdgcn_s_sleep(2);
      // acquire: invalidate stale cache lines before reading h
      (void)__hip_atomic_load(&pflag[l * TPL + L], __ATOMIC_ACQUIRE,
                              __HIP_MEMORY_SCOPE_AGENT);
    }
    __syncthreads();

    // ---------- A fragments (2 row-tiles x 16 k-iters, independent loads) ----------
    f16x8 a[2][16];
    if (w < 2) {            // input operand
      if (l == 0) {
#pragma unroll
        for (int rt = 0; rt < 2; ++rt) {
          const float* r = x + ((size_t)(rt * 16 + crow) * LL + t) * HH + kofs + kgrp * 8;
#pragma unroll
          for (int j = 0; j < 16; ++j) a[rt][j] = cvt8(r + j * 32);
        }
      } else {
        const _Float16* hb =
            hbuf + ((size_t)((l - 1) * RS + (t & (RS - 1))) * BB) * HH + kofs + kgrp * 8;
#pragma unroll
        for (int rt = 0; rt < 2; ++rt)
#pragma unroll
          for (int j = 0; j < 16; ++j)
            a[rt][j] = *reinterpret_cast<const f16x8*>(hb + (size_t)(rt * 16 + crow) * HH + j * 32);
      }
    } else {                // hidden operand
      if (t == 0) {
#pragma unroll
        for (int rt = 0; rt < 2; ++rt) {
          const float* r = h0 + ((size_t)l * BB + rt * 16 + crow) * HH + kofs + kgrp * 8;
#pragma unroll
          for (int j = 0; j < 16; ++j) a[rt][j] = cvt8(r + j * 32);
        }
      } else {
        const _Float16* hb =
            hbuf + ((size_t)(l * RS + ((t - 1) & (RS - 1))) * BB) * HH + kofs + kgrp * 8;
#pragma unroll
        for (int rt = 0; rt < 2; ++rt)
#pragma unroll
          for (int j = 0; j < 16; ++j)
            a[rt][j] = *reinterpret_cast<const f16x8*>(hb + (size_t)(rt * 16 + crow) * HH + j * 32);
      }
    }

    // ---------- MFMA ----------
    f32x4 acc[2][2];
#pragma unroll
    for (int ct = 0; ct < 2; ++ct)
#pragma unroll
      for (int rt = 0; rt < 2; ++rt) acc[ct][rt] = (f32x4){0.f, 0.f, 0.f, 0.f};
#pragma unroll
    for (int j = 0; j < 16; ++j)
#pragma unroll
      for (int ct = 0; ct < 2; ++ct)
#pragma unroll
        for (int rt = 0; rt < 2; ++rt)
          acc[ct][rt] = __builtin_amdgcn_mfma_f32_16x16x32_f16(a[rt][j], wfrag[ct][j],
                                                               acc[ct][rt], 0, 0, 0);

    // ---------- cross-wave k-reduce via LDS ----------
#pragma unroll
    for (int ct = 0; ct < 2; ++ct)
#pragma unroll
      for (int rt = 0; rt < 2; ++rt)
#pragma unroll
        for (int r = 0; r < 4; ++r)
          red[w][rt][kgrp * 4 + r][ct * 16 + crow] = acc[ct][rt][r];
    __syncthreads();

    float v[4];
#pragma unroll
    for (int j = 0; j < 4; ++j) {
      float s = bias[j];
#pragma unroll
      for (int w2 = 0; w2 < 4; ++w2) s += red[w2][rb >> 4][rb & 15][c4 + j];
      v[j] = tanhf(s);
    }

    {  // h ring store (4 x f16 = 8B)
      f16x4 hv;
#pragma unroll
      for (int j = 0; j < 4; ++j) hv[j] = (_Float16)v[j];
      *reinterpret_cast<f16x4*>(
          hbuf + ((size_t)(l * RS + (t & (RS - 1))) * BB + rb) * HH + c0 + c4) = hv;
    }
    if (l == NL - 1) {
      f32x4 o = {v[0], v[1], v[2], v[3]};
      __builtin_nontemporal_store(
          o, reinterpret_cast<f32x4*>(out + ((size_t)rb * LL + t) * HH + c0 + c4));
    }
    if (t == LL - 1) {
      f32x4 o = {v[0], v[1], v[2], v[3]};
      __builtin_nontemporal_store(
          o, reinterpret_cast<f32x4*>(out + (size_t)BB * LL * HH +
                                      ((size_t)l * BB + rb) * HH + c0 + c4));
    }
    __syncthreads();   // all waves' stores drained (vmcnt(0) before s_barrier)

    // ---------- publish progress (single release store, no RMW) ----------
    if (tid == 0)
      __hip_atomic_store(&pflag[l * TPL + tile], (unsigned)(t + 1), __ATOMIC_RELEASE,
                         __HIP_MEMORY_SCOPE_AGENT);
  }
}

extern "C" void kernel_launch(void* const* d_in, const int* in_sizes, int n_in,
                              void* d_out, int out_size, void* d_ws, size_t ws_size,
                              hipStream_t stream) {
  const float* x  = (const float*)d_in[0];
  const float* h0 = (const float*)d_in[1];
  const float* WI = (const float*)d_in[2];
  const float* BI = (const float*)d_in[3];
  const float* WH = (const float*)d_in[4];
  const float* BH = (const float*)d_in[5];
  float* out = (float*)d_out;

  const size_t hbytes = (size_t)NL * RS * BB * HH * sizeof(_Float16);  // 2 MB
  _Float16* hbuf = (_Float16*)d_ws;
  unsigned* pflag = (unsigned*)((char*)d_ws + hbytes);

  hipMemsetAsync(pflag, 0, (size_t)NL * TPL * sizeof(unsigned), stream);
  rnn_persist<<<256, 256, 0, stream>>>(x, h0, WI, BI, WH, BH, out, hbuf, pflag);
}